// Round 3
// baseline (343.942 us; speedup 1.0000x reference)
//
#include <hip/hip_runtime.h>

// AdderNet 2D: out[n,co,ho,wo] = -sum_{ci,kh,kw} |x_pad - w|
// x: [16,64,56,56] f32, w: [64,64,3,3] f32, out: [16,64,56,56] f32.
// VALU-bound: 2 f32 instr per reduce elem (v_sub + v_add with |.| modifier).
// Issue floor ~47 us @2.4GHz. R2 was latency-bound (real VALU busy ~37%).
//
// Structure: lane = co. Block = 4 waves = 2 row-pairs x 2 ci-halves.
// Each wave: 2 output rows x 8 cols, 32 ci. Weights shared across the row
// pair (same co,ci) -> 288 essential VALU per ci per wave over 15 loads.
// x rows streamed one at a time (10 live floats) to stay under 64 VGPR.
// ci-halves merged via LDS-overlay reduction at the end.

#define NCI   64
#define LDSW  12    // padded LDS row stride (48B, float4-aligned, <=2-way bank alias)

// pre-kernel: w[co][ci][k] -> wt[ci][k4][co][4]  (k = k4*4+jj, k>=9 zero-pad)
__global__ void wt_transpose_kernel(const float* __restrict__ w, float* __restrict__ wt) {
    int idx = blockIdx.x * 256 + threadIdx.x;   // 64*3*64*4 = 49152
    if (idx >= NCI * 3 * 64 * 4) return;
    int ci  = idx / 768;
    int rem = idx % 768;
    int k4  = rem / 256;
    int r2  = rem % 256;
    int co  = r2 / 4;
    int jj  = r2 % 4;
    int k   = k4 * 4 + jj;
    wt[idx] = (k < 9) ? w[(co * NCI + ci) * 9 + k] : 0.0f;
}

#define LOADROW(xr, base)                                   \
    {                                                       \
        float4 A = *(const float4*)(base);                  \
        float4 B = *(const float4*)((base) + 4);            \
        float2 C = *(const float2*)((base) + 8);            \
        xr[0]=A.x; xr[1]=A.y; xr[2]=A.z; xr[3]=A.w;         \
        xr[4]=B.x; xr[5]=B.y; xr[6]=B.z; xr[7]=B.w;         \
        xr[8]=C.x; xr[9]=C.y;                               \
    }

#define TAPS(acc, xr, wreg, kh)                             \
    _Pragma("unroll")                                       \
    for (int kw = 0; kw < 3; ++kw) {                        \
        const float wv_ = wreg[(kh)*3 + kw];                \
        _Pragma("unroll")                                   \
        for (int s = 0; s < 8; ++s)                         \
            acc[s] += fabsf(xr[s + kw] - wv_);              \
    }

template <bool USE_WT>
__global__ __launch_bounds__(256, 8) void adder2d_main(
    const float* __restrict__ x, const float* __restrict__ w,
    const float* __restrict__ wt, float* __restrict__ out)
{
    __shared__ float lds[NCI * 6 * LDSW];   // 18 KiB; overlaid by reduction buf
    float* xs = lds;                         // [ci][6][LDSW]

    const int bid = blockIdx.x;
    const int n   = bid / 98;          // 14 row-tiles * 7 col-tiles
    const int t   = bid % 98;
    const int r0  = (t / 7) * 4;
    const int c0  = (t % 7) * 8;

    const int tid  = threadIdx.x;
    const int lane = tid & 63;         // = co
    const int g    = tid >> 6;         // wave 0..3
    const int p    = g & 1;            // row-pair: rows r0+2p, r0+2p+1
    const int h    = g >> 1;           // ci half

    // ---- stage x tile: rows r0-1..r0+4 (6), cols c0-1..c0+8 (10), all ci ----
    const float* xn = x + (size_t)n * NCI * 56 * 56;
    for (int idx = tid; idx < NCI * 6 * 10; idx += 256) {
        int ci  = idx / 60;
        int rem = idx % 60;
        int r   = rem / 10;
        int c   = rem % 10;
        int gh  = r0 + r - 1;
        int gw  = c0 + c - 1;
        float v = 0.f;
        if ((unsigned)gh < 56u && (unsigned)gw < 56u)
            v = xn[(ci * 56 + gh) * 56 + gw];
        xs[(ci * 6 + r) * LDSW + c] = v;
    }
    __syncthreads();

    float acc0[8], acc1[8];
    #pragma unroll
    for (int s = 0; s < 8; ++s) { acc0[s] = 0.f; acc1[s] = 0.f; }

    const float4* wt4 = (const float4*)wt;
    const int ci0   = h * 32;
    const int xbase = p * 2;   // local x-row base for this row pair

    for (int ci = ci0; ci < ci0 + 32; ++ci) {
        float wreg[12];
        if (USE_WT) {
            #pragma unroll
            for (int k4 = 0; k4 < 3; ++k4) {
                float4 q = wt4[(ci * 3 + k4) * 64 + lane];
                wreg[k4*4+0] = q.x; wreg[k4*4+1] = q.y;
                wreg[k4*4+2] = q.z; wreg[k4*4+3] = q.w;
            }
        } else {
            #pragma unroll
            for (int k = 0; k < 9; ++k)
                wreg[k] = w[(lane * NCI + ci) * 9 + k];
        }

        const float* rb = &xs[(ci * 6 + xbase) * LDSW];

        // stream 4 x-rows; row j feeds acc0 with kh=j (j<=2), acc1 with kh=j-1 (j>=1)
        {
            float xr[10]; LOADROW(xr, rb);
            TAPS(acc0, xr, wreg, 0);
        }
        {
            float xr[10]; LOADROW(xr, rb + LDSW);
            TAPS(acc0, xr, wreg, 1);
            TAPS(acc1, xr, wreg, 0);
        }
        {
            float xr[10]; LOADROW(xr, rb + 2 * LDSW);
            TAPS(acc0, xr, wreg, 2);
            TAPS(acc1, xr, wreg, 1);
        }
        {
            float xr[10]; LOADROW(xr, rb + 3 * LDSW);
            TAPS(acc1, xr, wreg, 2);
        }
    }

    // ---- merge ci-halves via LDS overlay: red[i 0..15][p][lane] ----
    __syncthreads();   // all xs reads done; safe to overlay
    float* red = lds;
    if (h == 1) {
        #pragma unroll
        for (int i = 0; i < 8; ++i) {
            red[((i    ) * 2 + p) * 64 + lane] = acc0[i];
            red[((i + 8) * 2 + p) * 64 + lane] = acc1[i];
        }
    }
    __syncthreads();
    if (h == 0) {
        #pragma unroll
        for (int i = 0; i < 8; ++i) {
            acc0[i] += red[((i    ) * 2 + p) * 64 + lane];
            acc1[i] += red[((i + 8) * 2 + p) * 64 + lane];
        }
        float* op = out + (((size_t)n * 64 + lane) * 56 + (r0 + 2 * p)) * 56 + c0;
        *(float4*)(op)          = make_float4(-acc0[0], -acc0[1], -acc0[2], -acc0[3]);
        *(float4*)(op + 4)      = make_float4(-acc0[4], -acc0[5], -acc0[6], -acc0[7]);
        *(float4*)(op + 56)     = make_float4(-acc1[0], -acc1[1], -acc1[2], -acc1[3]);
        *(float4*)(op + 56 + 4) = make_float4(-acc1[4], -acc1[5], -acc1[6], -acc1[7]);
    }
}

extern "C" void kernel_launch(void* const* d_in, const int* in_sizes, int n_in,
                              void* d_out, int out_size, void* d_ws, size_t ws_size,
                              hipStream_t stream) {
    const float* x = (const float*)d_in[0];
    const float* w = (const float*)d_in[1];
    float* out = (float*)d_out;
    float* wt  = (float*)d_ws;

    const size_t wt_bytes = (size_t)NCI * 3 * 64 * 4 * sizeof(float);  // 192 KiB
    const bool use_wt = ws_size >= wt_bytes;

    if (use_wt) {
        wt_transpose_kernel<<<(NCI * 3 * 64 * 4 + 255) / 256, 256, 0, stream>>>(w, wt);
        adder2d_main<true><<<16 * 98, 256, 0, stream>>>(x, w, wt, out);
    } else {
        adder2d_main<false><<<16 * 98, 256, 0, stream>>>(x, w, wt, out);
    }
}

// Round 4
// 142.348 us; speedup vs baseline: 2.4162x; 2.4162x over previous
//
#include <hip/hip_runtime.h>

// AdderNet 2D: out[n,co,ho,wo] = -sum_{ci,kh,kw} |x_pad - w|
// x: [16,64,56,56] f32, w: [64,64,3,3] f32, out: [16,64,56,56] f32.
// VALU-bound: 2 f32 instr per reduce elem (v_sub + v_add with |.| modifier).
// Issue floor ~47 us @2.4GHz.
//
// R3 lesson: __launch_bounds__(256,8) capped VGPR at 32 -> massive scratch
// spill (WRITE_SIZE 922 MB). Same structure with (256,4): ~50-70 live VGPRs
// fit, no spill, and 2 rows/wave gives 288 essential VALU per 15 loads.
//
// Structure: lane = co. Block = 4 waves = 2 row-pairs x 2 ci-halves.
// Wave: 2 output rows x 8 cols, 32 ci. Weights shared across the row pair.
// x rows streamed one at a time from LDS (wave-uniform broadcast reads).
// ci-halves merged via LDS-overlay reduction.

#define NCI   64
#define LDSW  12    // padded LDS row stride (48B, float4-aligned, <=2-way bank alias)

// pre-kernel: w[co][ci][k] -> wt[ci][k4][co][4]  (k = k4*4+jj, k>=9 zero-pad)
__global__ void wt_transpose_kernel(const float* __restrict__ w, float* __restrict__ wt) {
    int idx = blockIdx.x * 256 + threadIdx.x;   // 64*3*64*4 = 49152
    if (idx >= NCI * 3 * 64 * 4) return;
    int ci  = idx / 768;
    int rem = idx % 768;
    int k4  = rem / 256;
    int r2  = rem % 256;
    int co  = r2 / 4;
    int jj  = r2 % 4;
    int k   = k4 * 4 + jj;
    wt[idx] = (k < 9) ? w[(co * NCI + ci) * 9 + k] : 0.0f;
}

#define LOADROW(xr, base)                                   \
    {                                                       \
        float4 A = *(const float4*)(base);                  \
        float4 B = *(const float4*)((base) + 4);            \
        float2 C = *(const float2*)((base) + 8);            \
        xr[0]=A.x; xr[1]=A.y; xr[2]=A.z; xr[3]=A.w;         \
        xr[4]=B.x; xr[5]=B.y; xr[6]=B.z; xr[7]=B.w;         \
        xr[8]=C.x; xr[9]=C.y;                               \
    }

#define TAPS(acc, xr, wreg, kh)                             \
    _Pragma("unroll")                                       \
    for (int kw = 0; kw < 3; ++kw) {                        \
        const float wv_ = wreg[(kh)*3 + kw];                \
        _Pragma("unroll")                                   \
        for (int s = 0; s < 8; ++s)                         \
            acc[s] += fabsf(xr[s + kw] - wv_);              \
    }

template <bool USE_WT>
__global__ __launch_bounds__(256, 4) void adder2d_main(
    const float* __restrict__ x, const float* __restrict__ w,
    const float* __restrict__ wt, float* __restrict__ out)
{
    __shared__ float lds[NCI * 6 * LDSW];   // 18 KiB; overlaid by reduction buf
    float* xs = lds;                         // [ci][6][LDSW]

    const int bid = blockIdx.x;
    const int n   = bid / 98;          // 14 row-tiles * 7 col-tiles
    const int t   = bid % 98;
    const int r0  = (t / 7) * 4;
    const int c0  = (t % 7) * 8;

    const int tid  = threadIdx.x;
    const int lane = tid & 63;         // = co
    const int g    = tid >> 6;         // wave 0..3
    const int p    = g & 1;            // row-pair: rows r0+2p, r0+2p+1
    const int h    = g >> 1;           // ci half

    // ---- stage x tile: rows r0-1..r0+4 (6), cols c0-1..c0+8 (10), all ci ----
    const float* xn = x + (size_t)n * NCI * 56 * 56;
    for (int idx = tid; idx < NCI * 6 * 10; idx += 256) {
        int ci  = idx / 60;
        int rem = idx % 60;
        int r   = rem / 10;
        int c   = rem % 10;
        int gh  = r0 + r - 1;
        int gw  = c0 + c - 1;
        float v = 0.f;
        if ((unsigned)gh < 56u && (unsigned)gw < 56u)
            v = xn[(ci * 56 + gh) * 56 + gw];
        xs[(ci * 6 + r) * LDSW + c] = v;
    }
    __syncthreads();

    float acc0[8], acc1[8];
    #pragma unroll
    for (int s = 0; s < 8; ++s) { acc0[s] = 0.f; acc1[s] = 0.f; }

    const float4* wt4 = (const float4*)wt;
    const int ci0   = h * 32;
    const int xbase = p * 2;   // local x-row base for this row pair

    for (int ci = ci0; ci < ci0 + 32; ++ci) {
        float wreg[12];
        if (USE_WT) {
            #pragma unroll
            for (int k4 = 0; k4 < 3; ++k4) {
                float4 q = wt4[(ci * 3 + k4) * 64 + lane];
                wreg[k4*4+0] = q.x; wreg[k4*4+1] = q.y;
                wreg[k4*4+2] = q.z; wreg[k4*4+3] = q.w;
            }
        } else {
            #pragma unroll
            for (int k = 0; k < 9; ++k)
                wreg[k] = w[(lane * NCI + ci) * 9 + k];
        }

        const float* rb = &xs[(ci * 6 + xbase) * LDSW];

        // stream 4 x-rows; row j feeds acc0 with kh=j (j<=2), acc1 with kh=j-1 (j>=1)
        {
            float xr[10]; LOADROW(xr, rb);
            TAPS(acc0, xr, wreg, 0);
        }
        {
            float xr[10]; LOADROW(xr, rb + LDSW);
            TAPS(acc0, xr, wreg, 1);
            TAPS(acc1, xr, wreg, 0);
        }
        {
            float xr[10]; LOADROW(xr, rb + 2 * LDSW);
            TAPS(acc0, xr, wreg, 2);
            TAPS(acc1, xr, wreg, 1);
        }
        {
            float xr[10]; LOADROW(xr, rb + 3 * LDSW);
            TAPS(acc1, xr, wreg, 2);
        }
    }

    // ---- merge ci-halves via LDS overlay: red[i 0..15][p][lane] ----
    __syncthreads();   // all xs reads done; safe to overlay
    float* red = lds;
    if (h == 1) {
        #pragma unroll
        for (int i = 0; i < 8; ++i) {
            red[((i    ) * 2 + p) * 64 + lane] = acc0[i];
            red[((i + 8) * 2 + p) * 64 + lane] = acc1[i];
        }
    }
    __syncthreads();
    if (h == 0) {
        #pragma unroll
        for (int i = 0; i < 8; ++i) {
            acc0[i] += red[((i    ) * 2 + p) * 64 + lane];
            acc1[i] += red[((i + 8) * 2 + p) * 64 + lane];
        }
        float* op = out + (((size_t)n * 64 + lane) * 56 + (r0 + 2 * p)) * 56 + c0;
        *(float4*)(op)          = make_float4(-acc0[0], -acc0[1], -acc0[2], -acc0[3]);
        *(float4*)(op + 4)      = make_float4(-acc0[4], -acc0[5], -acc0[6], -acc0[7]);
        *(float4*)(op + 56)     = make_float4(-acc1[0], -acc1[1], -acc1[2], -acc1[3]);
        *(float4*)(op + 56 + 4) = make_float4(-acc1[4], -acc1[5], -acc1[6], -acc1[7]);
    }
}

extern "C" void kernel_launch(void* const* d_in, const int* in_sizes, int n_in,
                              void* d_out, int out_size, void* d_ws, size_t ws_size,
                              hipStream_t stream) {
    const float* x = (const float*)d_in[0];
    const float* w = (const float*)d_in[1];
    float* out = (float*)d_out;
    float* wt  = (float*)d_ws;

    const size_t wt_bytes = (size_t)NCI * 3 * 64 * 4 * sizeof(float);  // 192 KiB
    const bool use_wt = ws_size >= wt_bytes;

    if (use_wt) {
        wt_transpose_kernel<<<(NCI * 3 * 64 * 4 + 255) / 256, 256, 0, stream>>>(w, wt);
        adder2d_main<true><<<16 * 98, 256, 0, stream>>>(x, w, wt, out);
    } else {
        adder2d_main<false><<<16 * 98, 256, 0, stream>>>(x, w, wt, out);
    }
}